// Round 7
// baseline (312.619 us; speedup 1.0000x reference)
//
#include <hip/hip_runtime.h>
#include <hip/hip_bf16.h>
#include <hip/hip_cooperative_groups.h>

namespace cg = cooperative_groups;

// GQA: B=2, T=2048, EMB=2048, H=16, G=4, GS=4, HD=128, causal, eval-mode dropout.
// Single cooperative mega-kernel (512 blocks x 256 thr, 2 blocks/CU):
//   phase0 casts -> sync -> phase1 [Q|K] + V^T proj -> sync -> phase2 attention
//   -> sync -> phase3 out proj (+bias, f32). Fallback: 4-dispatch path.

typedef unsigned short ushort_t;
typedef __bf16 bf16x8 __attribute__((ext_vector_type(8)));
typedef float f32x4 __attribute__((ext_vector_type(4)));

__device__ __forceinline__ ushort_t f2bf(float f) {
  union { float f; unsigned u; } x; x.f = f;
  unsigned r = x.u + 0x7fffu + ((x.u >> 16) & 1u);
  return (ushort_t)(r >> 16);
}

// ---------------- cast helpers ----------------
__device__ __forceinline__ void cast_plain(const float* __restrict__ in,
                                           ushort_t* __restrict__ out, int i) {
  float4 v = reinterpret_cast<const float4*>(in)[i];
  ushort4 o;
  o.x = f2bf(v.x); o.y = f2bf(v.y); o.z = f2bf(v.z); o.w = f2bf(v.w);
  reinterpret_cast<ushort4*>(out)[i] = o;
}
// keep only rows g*512+d (d<128) -> compact 512x2048, row n = g*128+d
__device__ __forceinline__ void cast_cmp(const float* __restrict__ in,
                                         ushort_t* __restrict__ out, int i) {
  int row = i >> 9, c = i & 511;
  int srow = ((row >> 7) << 9) | (row & 127);
  float4 v = reinterpret_cast<const float4*>(in + (size_t)srow * 2048)[c];
  ushort4 o;
  o.x = f2bf(v.x); o.y = f2bf(v.y); o.z = f2bf(v.z); o.w = f2bf(v.w);
  reinterpret_cast<ushort4*>(out + (size_t)row * 2048)[c] = o;
}
__device__ __forceinline__ void cast_unit(int u, int tid,
                                          const float* x, const float* Wq, const float* Wk,
                                          const float* Wv, const float* Wp,
                                          ushort_t* xb, ushort_t* wqkb,
                                          ushort_t* wvb, ushort_t* wpb) {
  if (u < 8192)       cast_plain(x,  xb,  u * 256 + tid);
  else if (u < 12288) cast_plain(Wq, wqkb, (u - 8192) * 256 + tid);
  else if (u < 16384) cast_plain(Wp, wpb, (u - 12288) * 256 + tid);
  else if (u < 17408) cast_cmp(Wk, wqkb + (size_t)2048 * 2048, (u - 16384) * 256 + tid);
  else                cast_cmp(Wv, wvb, (u - 17408) * 256 + tid);
}

// ---------------- GEMM tile: C[M,N] = A[M,K] * B[N,K]^T ----------------
// 128x128 tile, BK=64, 4 waves (2x2 of 64x64). LDS row r stores 16B-chunk c at
// slot c^(r&7): pre-swizzled global source, linear gload_lds dest (rule-21).
template<bool FINAL>
__device__ __forceinline__ void gemm_tile(ushort_t* __restrict__ lA,   // [128*64]
                                          ushort_t* __restrict__ lB,   // [128*64]
                                          const ushort_t* __restrict__ A,
                                          const ushort_t* __restrict__ B,
                                          ushort_t* __restrict__ Cb,
                                          float* __restrict__ Cf,
                                          const float* __restrict__ bias,
                                          int m0, int n0, int N, int K) {
  const int lane = threadIdx.x & 63;
  const int w = threadIdx.x >> 6;
  const int wm = (w >> 1) * 64, wn = (w & 1) * 64;
  const int l4 = lane >> 4, l15 = lane & 15;

  const f32x4 zero = {0.f, 0.f, 0.f, 0.f};
  f32x4 acc[4][4];
#pragma unroll
  for (int i = 0; i < 4; ++i)
#pragma unroll
    for (int j = 0; j < 4; ++j) acc[i][j] = zero;

  const int srow = w * 8 + (lane >> 3);                    // row&7 == lane>>3
  const int scol = ((lane & 7) ^ (lane >> 3)) * 8;
  const ushort_t* ga = A + (size_t)(m0 + srow) * K + scol;
  const ushort_t* gb = B + (size_t)(n0 + srow) * K + scol;

  for (int kt = 0; kt < K; kt += 64) {
#pragma unroll
    for (int i = 0; i < 4; ++i) {
      __builtin_amdgcn_global_load_lds(
          (const __attribute__((address_space(1))) void*)(ga + (size_t)i * 32 * K + kt),
          (__attribute__((address_space(3))) void*)(&lA[i * 2048 + w * 512]), 16, 0, 0);
      __builtin_amdgcn_global_load_lds(
          (const __attribute__((address_space(1))) void*)(gb + (size_t)i * 32 * K + kt),
          (__attribute__((address_space(3))) void*)(&lB[i * 2048 + w * 512]), 16, 0, 0);
    }
    __syncthreads();  // drains vmcnt + barrier
#pragma unroll
    for (int kk = 0; kk < 2; ++kk) {
      bf16x8 af[4], bfr[4];
#pragma unroll
      for (int t = 0; t < 4; ++t) {
        const int Ra = wm + t * 16 + l15;
        const int Rb = wn + t * 16 + l15;
        af[t]  = *reinterpret_cast<const bf16x8*>(&lA[Ra * 64 + ((kk * 4 + l4) ^ (Ra & 7)) * 8]);
        bfr[t] = *reinterpret_cast<const bf16x8*>(&lB[Rb * 64 + ((kk * 4 + l4) ^ (Rb & 7)) * 8]);
      }
#pragma unroll
      for (int mi = 0; mi < 4; ++mi)
#pragma unroll
        for (int ni = 0; ni < 4; ++ni)
          acc[mi][ni] = __builtin_amdgcn_mfma_f32_16x16x32_bf16(af[mi], bfr[ni],
                                                                acc[mi][ni], 0, 0, 0);
    }
    __syncthreads();
  }

#pragma unroll
  for (int mi = 0; mi < 4; ++mi)
#pragma unroll
    for (int ni = 0; ni < 4; ++ni) {
      int row = m0 + wm + mi * 16 + l4 * 4;
      int col = n0 + wn + ni * 16 + l15;
#pragma unroll
      for (int r = 0; r < 4; ++r) {
        float v = acc[mi][ni][r];
        if (FINAL) Cf[(size_t)(row + r) * N + col] = v + bias[col];
        else       Cb[(size_t)(row + r) * N + col] = f2bf(v);
      }
    }
}

__device__ __forceinline__ void proj_unit(int t, ushort_t* lA, ushort_t* lB,
                                          const ushort_t* xb, const ushort_t* wqkb,
                                          const ushort_t* wvb, ushort_t* qkbuf,
                                          ushort_t* vtb) {
  if (t < 640) {
    gemm_tile<false>(lA, lB, xb, wqkb, qkbuf, nullptr, nullptr,
                     (t / 20) * 128, (t % 20) * 128, 2560, 2048);
  } else {
    int u = t - 640;
    gemm_tile<false>(lA, lB, wvb, xb, vtb, nullptr, nullptr,
                     (u / 32) * 128, (u % 32) * 128, 4096, 2048);
  }
}

// ---------------- flash attention body (identical math to round 5/6) ----------
// ldsK: [2][64*128] (32KB), ldsV: [2][128*64] (32KB), pbufA: [4][16*72] (9216B)
__device__ __forceinline__ void attn_body(ushort_t* __restrict__ ldsK,
                                          ushort_t* __restrict__ ldsV,
                                          ushort_t* __restrict__ pbufA,
                                          const ushort_t* __restrict__ Qb, int ldQ,
                                          const ushort_t* __restrict__ Kb, int ldK,
                                          const ushort_t* __restrict__ Vt,
                                          ushort_t* __restrict__ Ob) {
  const int lane = threadIdx.x & 63;
  const int w = threadIdx.x >> 6;
  ushort_t* pbuf = pbufA + w * 1152;
  const int swz = ((blockIdx.x & 7) << 6) | (blockIdx.x >> 3);  // chunked XCD swizzle
  const int b = swz >> 8, hq = (swz >> 4) & 15, pair = swz & 15;
  const int g = hq >> 2;
  const int l4 = lane >> 4, l15 = lane & 15;
  const int tau_hi = 31 - pair, tau_lo = pair;
  const int hi_iters = tau_hi + 1;
  const int total_iters = hi_iters + tau_lo + 1;  // == 33 for all blocks
  const float C = 0.12751744f;              // (1/sqrt(128)) * log2(e)

  const int krow = w * 4 + (lane >> 4);
  const ushort_t* kBase = Kb + (size_t)(b * 2048 + krow) * ldK + g * 128 + ((lane & 15) ^ (krow & 7)) * 8;
  const int vrow = w * 8 + (lane >> 3);
  const ushort_t* vBase = Vt + (size_t)(g * 128 + vrow) * 4096 + b * 2048 + ((lane & 7) ^ (vrow & 7)) * 8;

  const f32x4 zero = {0.f, 0.f, 0.f, 0.f};
  f32x4 o[8];
  float mr[4], lr[4];
  bf16x8 qf[4];

  auto LOADQ = [&](int tau) {
    const ushort_t* qp = Qb + (size_t)(b * 2048 + tau * 64 + w * 16 + l15) * ldQ + hq * 128 + l4 * 8;
#pragma unroll
    for (int kk = 0; kk < 4; ++kk) {
      bf16x8 q = *reinterpret_cast<const bf16x8*>(qp + kk * 32);
#pragma unroll
      for (int j = 0; j < 8; ++j) q[j] = (__bf16)((float)q[j] * C);
      qf[kk] = q;
    }
  };
  auto RESET = [&]() {
#pragma unroll
    for (int i = 0; i < 8; ++i) o[i] = zero;
#pragma unroll
    for (int r = 0; r < 4; ++r) { mr[r] = -3.0e38f; lr[r] = 0.f; }
  };
  auto STAGE = [&](int tt, int bc) {
    const int js = (tt < hi_iters) ? tt * 64 : (tt - hi_iters) * 64;
    const ushort_t* ks = kBase + (size_t)js * ldK;
    const ushort_t* vs = vBase + js;
#pragma unroll
    for (int i = 0; i < 4; ++i) {
      __builtin_amdgcn_global_load_lds(
          (const __attribute__((address_space(1))) void*)(ks + (size_t)i * 16 * ldK),
          (__attribute__((address_space(3))) void*)(&ldsK[bc * 8192 + i * 2048 + w * 512]), 16, 0, 0);
      __builtin_amdgcn_global_load_lds(
          (const __attribute__((address_space(1))) void*)(vs + (size_t)i * 32 * 4096),
          (__attribute__((address_space(3))) void*)(&ldsV[bc * 8192 + i * 2048 + w * 512]), 16, 0, 0);
    }
  };
  auto FINALIZE = [&](int tau) {
#pragma unroll
    for (int r = 0; r < 4; ++r) {
#pragma unroll
      for (int d = 1; d < 16; d <<= 1) lr[r] += __shfl_xor(lr[r], d, 16);
      lr[r] = 1.0f / lr[r];
    }
    ushort_t* op = Ob + (size_t)(b * 2048 + tau * 64 + w * 16) * 2048 + hq * 128;
#pragma unroll
    for (int ni = 0; ni < 8; ++ni)
#pragma unroll
      for (int r = 0; r < 4; ++r)
        op[(size_t)(l4 * 4 + r) * 2048 + ni * 16 + l15] = f2bf(o[ni][r] * lr[r]);
  };

  RESET();
  LOADQ(tau_hi);
  STAGE(0, 0);

  for (int t = 0; t < total_iters; ++t) {
    if (t == hi_iters) {
      FINALIZE(tau_hi);
      RESET();
      LOADQ(tau_lo);
    }
    __syncthreads();
    if (t + 1 < total_iters) STAGE(t + 1, (t + 1) & 1);
    const int bc = t & 1;

    const int tau = (t < hi_iters) ? tau_hi : tau_lo;
    const int tloc = (t < hi_iters) ? t : (t - hi_iters);
    const int j0 = tloc * 64;
    const int q0 = tau * 64 + w * 16;
    const bool diag = (tloc == tau);

    f32x4 s[4];
#pragma unroll
    for (int i = 0; i < 4; ++i) s[i] = zero;
#pragma unroll
    for (int ni = 0; ni < 4; ++ni) {
      const int R = ni * 16 + l15;
#pragma unroll
      for (int kk = 0; kk < 4; ++kk) {
        bf16x8 kf = *reinterpret_cast<const bf16x8*>(
            &ldsK[bc * 8192 + R * 128 + ((kk * 4 + l4) ^ (R & 7)) * 8]);
        s[ni] = __builtin_amdgcn_mfma_f32_16x16x32_bf16(qf[kk], kf, s[ni], 0, 0, 0);
      }
    }
    float pmax[4] = {-3.0e38f, -3.0e38f, -3.0e38f, -3.0e38f};
    if (diag) {
#pragma unroll
      for (int ni = 0; ni < 4; ++ni) {
        int col = j0 + ni * 16 + l15;
#pragma unroll
        for (int r = 0; r < 4; ++r) {
          int qq = q0 + l4 * 4 + r;
          float v = (col <= qq) ? s[ni][r] : -3.0e38f;
          s[ni][r] = v;
          pmax[r] = fmaxf(pmax[r], v);
        }
      }
    } else {
#pragma unroll
      for (int ni = 0; ni < 4; ++ni)
#pragma unroll
        for (int r = 0; r < 4; ++r) pmax[r] = fmaxf(pmax[r], s[ni][r]);
    }
    bool small = (pmax[0] <= mr[0] + 8.f) & (pmax[1] <= mr[1] + 8.f) &
                 (pmax[2] <= mr[2] + 8.f) & (pmax[3] <= mr[3] + 8.f);
    if (!__all(small)) {
#pragma unroll
      for (int r = 0; r < 4; ++r) {
#pragma unroll
        for (int d = 1; d < 16; d <<= 1) pmax[r] = fmaxf(pmax[r], __shfl_xor(pmax[r], d, 16));
        float mn = fmaxf(mr[r], pmax[r]);
        float corr = exp2f(mr[r] - mn);
        mr[r] = mn;
        lr[r] *= corr;
#pragma unroll
        for (int i = 0; i < 8; ++i) o[i][r] *= corr;
      }
    }
#pragma unroll
    for (int ni = 0; ni < 4; ++ni)
#pragma unroll
      for (int r = 0; r < 4; ++r) {
        float p = exp2f(s[ni][r] - mr[r]);
        lr[r] += p;
        pbuf[(l4 * 4 + r) * 72 + ni * 16 + l15] = f2bf(p);
      }
    bf16x8 pa[2];
#pragma unroll
    for (int kk2 = 0; kk2 < 2; ++kk2)
      pa[kk2] = *reinterpret_cast<const bf16x8*>(&pbuf[l15 * 72 + kk2 * 32 + l4 * 8]);
#pragma unroll
    for (int ni = 0; ni < 8; ++ni) {
      const int R = ni * 16 + l15;
#pragma unroll
      for (int kk2 = 0; kk2 < 2; ++kk2) {
        bf16x8 vf = *reinterpret_cast<const bf16x8*>(
            &ldsV[bc * 8192 + R * 64 + ((kk2 * 4 + l4) ^ (R & 7)) * 8]);
        o[ni] = __builtin_amdgcn_mfma_f32_16x16x32_bf16(pa[kk2], vf, o[ni], 0, 0, 0);
      }
    }
  }
  FINALIZE(tau_lo);
}

// ---------------- mega kernel (cooperative, 512 blocks x 256 thr) -------------
__global__ __launch_bounds__(256, 2) void mega_kernel(
    const float* __restrict__ x, const float* __restrict__ Wq,
    const float* __restrict__ Wk, const float* __restrict__ Wv,
    const float* __restrict__ Wp, const float* __restrict__ bp,
    float* __restrict__ out,
    ushort_t* xb, ushort_t* wqkb, ushort_t* wvb, ushort_t* wpb,
    ushort_t* qkbuf, ushort_t* vtb, ushort_t* obuf) {
  extern __shared__ ushort_t smem[];   // 74752 B
  cg::grid_group gg = cg::this_grid();
  const int tid = threadIdx.x;

  // phase 0: casts (18432 units)
  for (int u = blockIdx.x; u < 18432; u += 512)
    cast_unit(u, tid, x, Wq, Wk, Wv, Wp, xb, wqkb, wvb, wpb);
  gg.sync();

  // phase 1: projections (768 tiles: 640 [Q|K] + 128 V^T)
  for (int t = blockIdx.x; t < 768; t += 512)
    proj_unit(t, smem, smem + 8192, xb, wqkb, wvb, qkbuf, vtb);
  gg.sync();

  // phase 2: attention (512 blocks, 1:1)
  attn_body(smem, smem + 16384, smem + 32768,
            qkbuf, 2560, qkbuf + 2048, 2560, vtb, obuf);
  gg.sync();

  // phase 3: out = O Wp^T + bp (512 tiles, 1:1)
  gemm_tile<true>(smem, smem + 8192, obuf, wpb, nullptr, out, bp,
                  ((int)blockIdx.x >> 4) * 128, ((int)blockIdx.x & 15) * 128,
                  2048, 2048);
}

// ---------------- legacy 4-dispatch fallback kernels ----------------
__global__ __launch_bounds__(256) void cast_all(const float* __restrict__ x,
                                                const float* __restrict__ Wq,
                                                const float* __restrict__ Wk,
                                                const float* __restrict__ Wv,
                                                const float* __restrict__ Wp,
                                                ushort_t* __restrict__ xb,
                                                ushort_t* __restrict__ wqkb,
                                                ushort_t* __restrict__ wvb,
                                                ushort_t* __restrict__ wpb) {
  cast_unit(blockIdx.x, threadIdx.x, x, Wq, Wk, Wv, Wp, xb, wqkb, wvb, wpb);
}

__global__ __launch_bounds__(256) void proj_fused(const ushort_t* __restrict__ xb,
                                                  const ushort_t* __restrict__ wqkb,
                                                  const ushort_t* __restrict__ wvb,
                                                  ushort_t* __restrict__ qkbuf,
                                                  ushort_t* __restrict__ vtb) {
  __shared__ ushort_t lds[2 * 128 * 64];
  proj_unit(blockIdx.x, lds, lds + 8192, xb, wqkb, wvb, qkbuf, vtb);
}

__global__ __launch_bounds__(256, 2) void attn_kernel(const ushort_t* __restrict__ Qb, int ldQ,
                                                      const ushort_t* __restrict__ Kb, int ldK,
                                                      const ushort_t* __restrict__ Vt,
                                                      ushort_t* __restrict__ Ob) {
  __shared__ ushort_t s[37376];
  attn_body(s, s + 16384, s + 32768, Qb, ldQ, Kb, ldK, Vt, Ob);
}

__global__ __launch_bounds__(256) void gemm_final(const ushort_t* __restrict__ A,
                                                  const ushort_t* __restrict__ B,
                                                  float* __restrict__ Cf,
                                                  const float* __restrict__ bias) {
  __shared__ ushort_t lds[2 * 128 * 64];
  gemm_tile<true>(lds, lds + 8192, A, B, nullptr, Cf, bias,
                  (int)blockIdx.y * 128, (int)blockIdx.x * 128, 2048, 2048);
}

// ---------------- launch ----------------
extern "C" void kernel_launch(void* const* d_in, const int* in_sizes, int n_in,
                              void* d_out, int out_size, void* d_ws, size_t ws_size,
                              hipStream_t stream) {
  const float* x  = (const float*)d_in[0];
  const float* Wq = (const float*)d_in[1];
  const float* Wk = (const float*)d_in[2];
  const float* Wv = (const float*)d_in[3];
  const float* Wp = (const float*)d_in[4];
  const float* bp = (const float*)d_in[5];
  float* out = (float*)d_out;

  char* ws = (char*)d_ws;
  size_t off = 0;
  ushort_t* xb    = (ushort_t*)(ws + off); off += (size_t)4096 * 2048 * 2;
  ushort_t* wqkb  = (ushort_t*)(ws + off); off += (size_t)2560 * 2048 * 2;  // [Wq; Wk_c]
  ushort_t* wvb   = (ushort_t*)(ws + off); off += (size_t)512 * 2048 * 2;
  ushort_t* wpb   = (ushort_t*)(ws + off); off += (size_t)2048 * 2048 * 2;
  ushort_t* qkbuf = (ushort_t*)(ws + off); off += (size_t)4096 * 2560 * 2;  // Q | K
  ushort_t* vtb   = (ushort_t*)(ws + off); off += (size_t)512 * 4096 * 2;
  ushort_t* obuf  = (ushort_t*)(ws + off); off += (size_t)4096 * 2048 * 2;

  // deterministic host-side check (same result every call): can 512 coop blocks
  // be co-resident (2/CU)? If yes use mega kernel, else proven 4-dispatch path.
  int nb = 0;
  hipOccupancyMaxActiveBlocksPerMultiprocessor(&nb, mega_kernel, 256, (size_t)74752);
  if (nb >= 2) {
    void* args[] = {(void*)&x, (void*)&Wq, (void*)&Wk, (void*)&Wv, (void*)&Wp,
                    (void*)&bp, (void*)&out, (void*)&xb, (void*)&wqkb, (void*)&wvb,
                    (void*)&wpb, (void*)&qkbuf, (void*)&vtb, (void*)&obuf};
    hipLaunchCooperativeKernel(mega_kernel, dim3(512), dim3(256), args,
                               (unsigned)74752, stream);
  } else {
    cast_all<<<18432, 256, 0, stream>>>(x, Wq, Wk, Wv, Wp, xb, wqkb, wvb, wpb);
    proj_fused<<<768, 256, 0, stream>>>(xb, wqkb, wvb, qkbuf, vtb);
    attn_kernel<<<512, 256, 0, stream>>>(qkbuf, 2560, qkbuf + 2048, 2560, vtb, obuf);
    gemm_final<<<dim3(16, 32), 256, 0, stream>>>(obuf, wpb, out, bp);
  }
}